// Round 6
// baseline (53.968 us; speedup 1.0000x reference)
//
#include <hip/hip_runtime.h>

#define WPTS 801
#define ROWS 16
#define NT 256

typedef float v2f __attribute__((ext_vector_type(2)));

struct c2 { float x, y; };

__device__ __forceinline__ c2 c_addc(c2 a, c2 b) { return {a.x + b.x, a.y + b.y}; }
__device__ __forceinline__ c2 c_subc(c2 a, c2 b) { return {a.x - b.x, a.y - b.y}; }
__device__ __forceinline__ c2 c_divc(c2 a, c2 b) {
    float inv = 1.0f / (b.x * b.x + b.y * b.y);
    return {(a.x * b.x + a.y * b.y) * inv, (a.y * b.x - a.x * b.y) * inv};
}

// Packed FP32 (CDNA full-rate, 2 rows per instruction).
// Every asm has at most ONE SGPR operand (HW limit: 1 scalar read / vector inst).
#define PKMUL(d, a, b)      asm("v_pk_mul_f32 %0, %1, %2"     : "=v"(d) : "v"(a), "v"(b))
#define PKMULS(d, a, bs)    asm("v_pk_mul_f32 %0, %1, %2"     : "=v"(d) : "v"(a), "s"(bs))
#define PKFMA(d, a, b, c)   asm("v_pk_fma_f32 %0, %1, %2, %3" : "=v"(d) : "v"(a), "v"(b), "v"(c))
#define PKFMAS(d, a, b, cs) asm("v_pk_fma_f32 %0, %1, %2, %3" : "=v"(d) : "v"(a), "v"(b), "s"(cs))

__global__ __launch_bounds__(NT)
void kla_tmm_kernel(const float* __restrict__ d_phys,
                    const float* __restrict__ nSi_f,
                    const float* __restrict__ nSiO2_f,
                    const float* __restrict__ nSi3N4_f,
                    const float* __restrict__ lam,
                    float* __restrict__ out,
                    int B)
{
    const int nRowBlks = (B + ROWS - 1) / ROWS;
    const int t = blockIdx.x * NT + threadIdx.x;
    if (t >= nRowBlks * WPTS) return;

    const int w = t % WPTS;
    const int row0 = (t / WPTS) * ROWS;
    const int nrows = min(ROWS, B - row0);

    // ---- Layout-robust complex reads (same detection as passing r2-r5) ----
    const bool ilv = (nSiO2_f[1] == 0.0f);
    float nSx, nSy, nOx, nOy, nNx, nNy;
    if (ilv) {
        nSx = nSi_f[2 * w];    nSy = nSi_f[2 * w + 1];
        nOx = nSiO2_f[2 * w];  nOy = nSiO2_f[2 * w + 1];
        nNx = nSi3N4_f[2 * w]; nNy = nSi3N4_f[2 * w + 1];
    } else {
        nSx = nSi_f[w];    nSy = 0.0f;
        nOx = nSiO2_f[w];  nOy = 0.0f;
        nNx = nSi3N4_f[w]; nNy = 0.0f;
    }

    const float k0 = 6.28318530717958647692f / lam[w];
    const bool realn = (nOy == 0.0f) && (nNy == 0.0f) && (nSy == 0.0f);

    if (realn && nrows == ROWS) {
        // ======== real-n fast path: explicit v_pk_*_f32, 2 rows/inst ========
        const float rAO  = (1.0f - nOx) / (1.0f + nOx);
        const float rON  = (nOx - nNx) / (nOx + nNx);
        const float rNO  = -rON;
        const float rOSi = (nOx - nSx) / (nOx + nSx);
        const float invpi = 0.318309886183790672f;
        const float kOpi = k0 * nOx * invpi;   // nu = d * kpi;  phase = pi*nu
        const float kNpi = k0 * nNx * invpi;

        // Per-thread broadcast pairs (VGPR)
        const v2f rAOp = {rAO, rAO};
        const v2f rONp = {rON, rON};
        const v2f rNOp = {rNO, rNO};
        const v2f A9p  = {0.08214588661113f, 0.08214588661113f};
        const v2f C8p  = {0.23533063035889f, 0.23533063035889f};

        // Uniform poly constants (SGPR pairs)
        const v2f sA7 = {-0.59926452932079f, -0.59926452932079f};
        const v2f sA5 = { 2.55016403987735f,  2.55016403987735f};
        const v2f sA3 = {-5.16771278004997f, -5.16771278004997f};
        const v2f sA1 = { 3.14159265358979f,  3.14159265358979f};
        const v2f sC6 = {-1.33526276885459f, -1.33526276885459f};
        const v2f sC4 = { 4.05871212641677f,  4.05871212641677f};
        const v2f sC2 = {-4.93480220054468f, -4.93480220054468f};
        const v2f sOne  = { 1.0f,  1.0f};
        const v2f sNeg1 = {-1.0f, -1.0f};

        const float* base = d_phys + (size_t)row0 * 7;
        float* orow = out + (size_t)row0 * WPTS + w;

        #pragma unroll
        for (int p = 0; p < ROWS / 2; ++p) {
            const float* dA = base + (size_t)(2 * p) * 7;
            const float* dB = dA + 7;

            v2f u0x = {1.0f, 1.0f};
            v2f u0y = {0.0f, 0.0f};
            v2f u1x = {rOSi, rOSi};
            v2f u1y = {0.0f, 0.0f};

            #pragma unroll
            for (int i = 7; i >= 1; --i) {
                const float kpi = (i & 1) ? kOpi : kNpi;
                v2f dp;
                dp.x = dA[i - 1];
                dp.y = dB[i - 1];
                // nu, rint, t in plain C (scalar rndne; cheap).
                // Parity sign of (c,s) flips (u0,u1) jointly -> cancels in R.
                v2f nu = dp * kpi;
                v2f rv;
                rv.x = __builtin_rintf(nu.x);
                rv.y = __builtin_rintf(nu.y);
                v2f tt = nu - rv;

                v2f q, ps, pc, sv, cv, ns;
                PKMUL(q, tt, tt);
                // sin(pi t): t*(A1 + q(A3 + q(A5 + q(A7 + q A9))))
                PKFMAS(ps, q, A9p, sA7);
                PKFMAS(ps, q, ps,  sA5);
                PKFMAS(ps, q, ps,  sA3);
                PKFMAS(ps, q, ps,  sA1);
                PKMUL(sv, tt, ps);
                // cos(pi t): 1 + q(C2 + q(C4 + q(C6 + q C8)))
                PKFMAS(pc, q, C8p, sC6);
                PKFMAS(pc, q, pc,  sC4);
                PKFMAS(pc, q, pc,  sC2);
                PKFMAS(cv, q, pc,  sOne);
                PKMULS(ns, sv, sNeg1);       // -s

                // rotate: u0 *= (c - i s); u1 *= (c + i s)
                v2f m0, m1, m2, m3, t0x, t0y, t1x, t1y;
                PKMUL(m0, u0x, cv); PKFMA(t0x, u0y, sv, m0);
                PKMUL(m1, u0y, cv); PKFMA(t0y, u0x, ns, m1);
                PKMUL(m2, u1x, cv); PKFMA(t1x, u1y, ns, m2);
                PKMUL(m3, u1y, cv); PKFMA(t1y, u1x, sv, m3);

                // interface (real r): u0' = t0 + r t1 ; u1' = t1 + r t0
                const v2f rp = (i == 1) ? rAOp : ((i & 1) ? rNOp : rONp);
                PKFMA(u0x, rp, t1x, t0x);
                PKFMA(u0y, rp, t1y, t0y);
                PKFMA(u1x, rp, t0x, t1x);
                PKFMA(u1y, rp, t0y, t1y);
            }

            v2f n1, num, d1, den;
            PKMUL(n1, u1x, u1x); PKFMA(num, u1y, u1y, n1);
            PKMUL(d1, u0x, u0x); PKFMA(den, u0y, u0y, d1);
            orow[(size_t)(2 * p) * WPTS]     = num.x * __builtin_amdgcn_rcpf(den.x);
            orow[(size_t)(2 * p + 1) * WPTS] = num.y * __builtin_amdgcn_rcpf(den.y);
        }
    } else {
        // ======== general complex path (round-2 code, known correct) ========
        const c2 nA = {1.0f, 0.0f};
        const c2 nO = {nOx, nOy}, nN = {nNx, nNy}, nS = {nSx, nSy};
        const c2 rAO  = c_divc(c_subc(nA, nO), c_addc(nA, nO));
        const c2 rON  = c_divc(c_subc(nO, nN), c_addc(nO, nN));
        const c2 rNO  = {-rON.x, -rON.y};
        const c2 rOSi = c_divc(c_subc(nO, nS), c_addc(nO, nS));
        const c2 kO = {k0 * nO.x, k0 * nO.y};
        const c2 kN = {k0 * nN.x, k0 * nN.y};

        for (int rr = 0; rr < nrows; ++rr) {
            const int row = row0 + rr;
            const float* dd = d_phys + (size_t)row * 7;

            c2 u0 = {1.0f, 0.0f};
            c2 u1 = rOSi;

            #pragma unroll
            for (int i = 7; i >= 1; --i) {
                const float d = dd[i - 1];
                const c2 kk = (i & 1) ? kO : kN;
                const float alpha = kk.x * d;
                const float beta  = kk.y * d;
                float s, c;
                __sincosf(alpha, &s, &c);
                const float ep = __expf(beta);
                const float em = __expf(-beta);

                c2 v;
                v.x = ep * (u0.x * c + u0.y * s);
                v.y = ep * (u0.y * c - u0.x * s);
                u0 = v;
                v.x = em * (u1.x * c - u1.y * s);
                v.y = em * (u1.y * c + u1.x * s);
                u1 = v;

                const c2 ri = (i == 1) ? rAO : ((i & 1) ? rNO : rON);
                c2 w0, w1;
                w0.x = u0.x + ri.x * u1.x - ri.y * u1.y;
                w0.y = u0.y + ri.x * u1.y + ri.y * u1.x;
                w1.x = u1.x + ri.x * u0.x - ri.y * u0.y;
                w1.y = u1.y + ri.x * u0.y + ri.y * u0.x;
                u0 = w0; u1 = w1;
            }

            out[(size_t)row * WPTS + w] =
                (u1.x * u1.x + u1.y * u1.y) / (u0.x * u0.x + u0.y * u0.y);
        }
    }
}

extern "C" void kernel_launch(void* const* d_in, const int* in_sizes, int n_in,
                              void* d_out, int out_size, void* d_ws, size_t ws_size,
                              hipStream_t stream) {
    const float* d_phys  = (const float*)d_in[0];
    const float* nSi     = (const float*)d_in[1];
    const float* nSiO2   = (const float*)d_in[2];
    const float* nSi3N4  = (const float*)d_in[3];
    const float* lam     = (const float*)d_in[4];
    float* out = (float*)d_out;

    const int B = in_sizes[0] / 7;
    const int nRowBlks = (B + ROWS - 1) / ROWS;
    const int nTasks = nRowBlks * WPTS;
    const int grid = (nTasks + NT - 1) / NT;

    kla_tmm_kernel<<<grid, NT, 0, stream>>>(
        d_phys, nSi, nSiO2, nSi3N4, lam, out, B);
}

// Round 7
// 47.400 us; speedup vs baseline: 1.1386x; 1.1386x over previous
//
#include <hip/hip_runtime.h>

#define WPTS 801
#define ROWS 4
#define NT 256

struct c2 { float x, y; };

__device__ __forceinline__ c2 c_addc(c2 a, c2 b) { return {a.x + b.x, a.y + b.y}; }
__device__ __forceinline__ c2 c_subc(c2 a, c2 b) { return {a.x - b.x, a.y - b.y}; }
__device__ __forceinline__ c2 c_divc(c2 a, c2 b) {
    float inv = 1.0f / (b.x * b.x + b.y * b.y);
    return {(a.x * b.x + a.y * b.y) * inv, (a.y * b.x - a.x * b.y) * inv};
}

__global__ __launch_bounds__(NT)
void kla_tmm_kernel(const float* __restrict__ d_phys,
                    const float* __restrict__ nSi_f,
                    const float* __restrict__ nSiO2_f,
                    const float* __restrict__ nSi3N4_f,
                    const float* __restrict__ lam,
                    float* __restrict__ out,
                    int B)
{
    const int nRowBlks = (B + ROWS - 1) / ROWS;
    const int t = blockIdx.x * NT + threadIdx.x;
    if (t >= nRowBlks * WPTS) return;

    const int w = t % WPTS;
    const int row0 = (t / WPTS) * ROWS;
    const int nrows = min(ROWS, B - row0);

    // ---- Layout-robust complex reads (same detection as passing r2-r6) ----
    const bool ilv = (nSiO2_f[1] == 0.0f);
    float nSx, nSy, nOx, nOy, nNx, nNy;
    if (ilv) {
        nSx = nSi_f[2 * w];    nSy = nSi_f[2 * w + 1];
        nOx = nSiO2_f[2 * w];  nOy = nSiO2_f[2 * w + 1];
        nNx = nSi3N4_f[2 * w]; nNy = nSi3N4_f[2 * w + 1];
    } else {
        nSx = nSi_f[w];    nSy = 0.0f;
        nOx = nSiO2_f[w];  nOy = 0.0f;
        nNx = nSi3N4_f[w]; nNy = 0.0f;
    }

    const bool realn = (nOy == 0.0f) && (nNy == 0.0f) && (nSy == 0.0f);

    if (realn && nrows == ROWS) {
        // ==== real-n fast path, v-basis (v0=u0+u1, v1=u0-u1) ====
        // Interface becomes DIAGONAL: v0 *= (1+r), v1 *= (1-r); ratio
        // (1+r)/(1-r) = N_prev/N_next, global factor cancels in R.
        // Phase in revolutions: nu = n*d/lambda, raw hw v_sin/v_cos.
        const float rlam = __builtin_amdgcn_rcpf(lam[w]);
        const float kOr = nOx * rlam;            // SiO2 phase: rev per nm
        const float kNr = nNx * rlam;            // Si3N4 phase: rev per nm
        const float gAO = __builtin_amdgcn_rcpf(nOx);   // Air |SiO2 : 1/nO
        const float gON = nOx * __builtin_amdgcn_rcpf(nNx); // SiO2|Si3N4: nO/nN
        const float gNO = nNx * gAO;                     // Si3N4|SiO2: nN/nO

        const float* base = d_phys + (size_t)row0 * 7;
        float* orow = out + (size_t)row0 * WPTS + w;

        #pragma unroll
        for (int rr = 0; rr < ROWS; ++rr) {
            const float* dd = base + (size_t)rr * 7;
            // init: u = T8 e0 -> (1+rOSi, 1-rOSi) ∝ (nO, nS)
            float v0x = nOx, v0y = 0.0f;
            float v1x = nSx, v1y = 0.0f;

            #pragma unroll
            for (int i = 7; i >= 1; --i) {
                const float nu = dd[i - 1] * ((i & 1) ? kOr : kNr);
                const float s = __builtin_amdgcn_sinf(nu);  // sin(2*pi*nu)
                const float c = __builtin_amdgcn_cosf(nu);
                // phase mix: v0' = c v0 - i s v1 ; v1' = c v1 - i s v0
                const float w0x = v0x * c + v1y * s;
                const float w0y = v0y * c - v1x * s;
                const float w1x = v1x * c + v0y * s;
                const float w1y = v1y * c - v0x * s;
                // interface: v0 *= gamma (v1 factor folded into global scale)
                const float g = (i == 1) ? gAO : ((i & 1) ? gNO : gON);
                v0x = w0x * g;
                v0y = w0y * g;
                v1x = w1x;
                v1y = w1y;
            }

            // R = |u1|^2/|u0|^2 = |v0-v1|^2 / |v0+v1|^2
            const float ax = v0x - v1x, ay = v0y - v1y;
            const float bx = v0x + v1x, by = v0y + v1y;
            const float num = ax * ax + ay * ay;
            const float den = bx * bx + by * by;
            orow[(size_t)rr * WPTS] = num * __builtin_amdgcn_rcpf(den);
        }
    } else {
        // ======== general complex path (round-2 code, known correct) ========
        const float k0 = 6.28318530717958647692f / lam[w];
        const c2 nA = {1.0f, 0.0f};
        const c2 nO = {nOx, nOy}, nN = {nNx, nNy}, nS = {nSx, nSy};
        const c2 rAO  = c_divc(c_subc(nA, nO), c_addc(nA, nO));
        const c2 rON  = c_divc(c_subc(nO, nN), c_addc(nO, nN));
        const c2 rNO  = {-rON.x, -rON.y};
        const c2 rOSi = c_divc(c_subc(nO, nS), c_addc(nO, nS));
        const c2 kO = {k0 * nO.x, k0 * nO.y};
        const c2 kN = {k0 * nN.x, k0 * nN.y};

        for (int rr = 0; rr < nrows; ++rr) {
            const int row = row0 + rr;
            const float* dd = d_phys + (size_t)row * 7;

            c2 u0 = {1.0f, 0.0f};
            c2 u1 = rOSi;

            #pragma unroll
            for (int i = 7; i >= 1; --i) {
                const float d = dd[i - 1];
                const c2 kk = (i & 1) ? kO : kN;
                const float alpha = kk.x * d;
                const float beta  = kk.y * d;
                float s, c;
                __sincosf(alpha, &s, &c);
                const float ep = __expf(beta);
                const float em = __expf(-beta);

                c2 v;
                v.x = ep * (u0.x * c + u0.y * s);
                v.y = ep * (u0.y * c - u0.x * s);
                u0 = v;
                v.x = em * (u1.x * c - u1.y * s);
                v.y = em * (u1.y * c + u1.x * s);
                u1 = v;

                const c2 ri = (i == 1) ? rAO : ((i & 1) ? rNO : rON);
                c2 w0, w1;
                w0.x = u0.x + ri.x * u1.x - ri.y * u1.y;
                w0.y = u0.y + ri.x * u1.y + ri.y * u1.x;
                w1.x = u1.x + ri.x * u0.x - ri.y * u0.y;
                w1.y = u1.y + ri.x * u0.y + ri.y * u0.x;
                u0 = w0; u1 = w1;
            }

            out[(size_t)row * WPTS + w] =
                (u1.x * u1.x + u1.y * u1.y) / (u0.x * u0.x + u0.y * u0.y);
        }
    }
}

extern "C" void kernel_launch(void* const* d_in, const int* in_sizes, int n_in,
                              void* d_out, int out_size, void* d_ws, size_t ws_size,
                              hipStream_t stream) {
    const float* d_phys  = (const float*)d_in[0];
    const float* nSi     = (const float*)d_in[1];
    const float* nSiO2   = (const float*)d_in[2];
    const float* nSi3N4  = (const float*)d_in[3];
    const float* lam     = (const float*)d_in[4];
    float* out = (float*)d_out;

    const int B = in_sizes[0] / 7;
    const int nRowBlks = (B + ROWS - 1) / ROWS;
    const int nTasks = nRowBlks * WPTS;
    const int grid = (nTasks + NT - 1) / NT;

    kla_tmm_kernel<<<grid, NT, 0, stream>>>(
        d_phys, nSi, nSiO2, nSi3N4, lam, out, B);
}